// Round 1
// baseline (200.444 us; speedup 1.0000x reference)
//
#include <hip/hip_runtime.h>
#include <math.h>

// Problem constants (from reference)
#define B_ 4
#define S_ 4096
#define D_ 128
#define N_ 16
#define CHUNK_ 128
#define NCHUNK_ (S_ / CHUNK_)   // 32

__device__ __forceinline__ float softplusf(float z) {
    // matches jax.nn.softplus: max(z,0) + log1p(exp(-|z|))
    return fmaxf(z, 0.0f) + log1pf(expf(-fabsf(z)));
}

// ---------------------------------------------------------------------------
// K1: per-row projections. xWD[b,t] = x@W_D + b_D ; Bm = x@W_B + b_B ;
//     Cm = x@W_C + b_C.  One block = 16 rows, 256 threads (16 rows x 16 cols).
// ---------------------------------------------------------------------------
__global__ __launch_bounds__(256) void k1_proj(
    const float* __restrict__ x,
    const float* __restrict__ W_B, const float* __restrict__ b_B,
    const float* __restrict__ W_C, const float* __restrict__ b_C,
    const float* __restrict__ W_D, const float* __restrict__ b_D,
    float* __restrict__ xWD, float* __restrict__ Bm, float* __restrict__ Cm)
{
    __shared__ float xs[16][129];   // +1 pad: row-parallel reads conflict-free
    const int row0 = blockIdx.x * 16;
    const int tid = threadIdx.x;

    #pragma unroll
    for (int i = 0; i < 8; ++i) {
        int idx = i * 256 + tid;                 // 0..2047
        xs[idx >> 7][idx & 127] = x[row0 * D_ + idx];
    }
    __syncthreads();

    const int r = tid >> 4;     // local row 0..15
    const int n = tid & 15;     // state col 0..15
    float a = 0.f, c = 0.f;
    #pragma unroll 4
    for (int k = 0; k < D_; ++k) {
        float xv = xs[r][k];
        a = fmaf(xv, W_B[k * N_ + n], a);
        c = fmaf(xv, W_C[k * N_ + n], c);
    }
    Bm[(row0 + r) * N_ + n] = a + b_B[n];
    Cm[(row0 + r) * N_ + n] = c + b_C[n];

    if (tid < 16) {
        float dsum = 0.f;
        #pragma unroll 4
        for (int k = 0; k < D_; ++k) dsum = fmaf(xs[tid][k], W_D[k], dsum);
        xWD[row0 + tid] = dsum + b_D[0];
    }
}

// ---------------------------------------------------------------------------
// K2: disc[b,d,t] = softplus(P[d] + xWD[b,t]); dcum = inclusive cumsum over t.
//     One wave (64 lanes) per (b,d) sequence; wave-scan in chunks of 64.
// ---------------------------------------------------------------------------
__global__ __launch_bounds__(64) void k2_scan_disc(
    const float* __restrict__ xWD, const float* __restrict__ P,
    float* __restrict__ disc, float* __restrict__ dcum)
{
    const int b = blockIdx.x / D_;
    const int d = blockIdx.x % D_;
    const int lane = threadIdx.x;
    const float Pd = P[d];
    const float* xw = xWD + b * S_;
    float* dp = disc + (size_t)(b * D_ + d) * S_;
    float* cp = dcum + (size_t)(b * D_ + d) * S_;

    float carry = 0.f;
    for (int it = 0; it < S_ / 64; ++it) {
        int t = it * 64 + lane;
        float sp0 = softplusf(Pd + xw[t]);
        float s = sp0;
        #pragma unroll
        for (int off = 1; off < 64; off <<= 1) {
            float o = __shfl_up(s, off);
            if (lane >= off) s += o;
        }
        float dc = carry + s;
        dp[t] = sp0;
        cp[t] = dc;
        carry = __shfl(dc, 63);
    }
}

// ---------------------------------------------------------------------------
// K3: the chunked scan over AinvsB.
//   PHASE_C == 0: compute per-chunk totals of AinvsB -> chunkSum
//   PHASE_C == 1: replay with carried prefix, form h, contract with C -> y
// Block = 256 threads = 16 d x 16 n (n fastest). Grid = B * NCHUNK * (D/16).
// ---------------------------------------------------------------------------
template <int PHASE_C>
__global__ __launch_bounds__(256) void k3_scan(
    const float* __restrict__ x, const float* __restrict__ Araw,
    const float* __restrict__ Bm, const float* __restrict__ Cm,
    const float* __restrict__ disc, const float* __restrict__ dcum,
    float* __restrict__ chunkSum, const float* __restrict__ carry,
    float* __restrict__ y)
{
    const int blk = blockIdx.x;
    const int dg = blk & 7;                 // d-group (D/16 = 8)
    const int ch = (blk >> 3) & (NCHUNK_ - 1);
    const int b  = blk >> 8;                // 3 + 5 bits
    const int tid = threadIdx.x;
    const int n = tid & 15;
    const int dl = tid >> 4;
    const int d = dg * 16 + dl;

    const float A  = -softplusf(Araw[d * N_ + n]);   // strictly negative
    const float rA = 1.0f / A;

    const float* dp = disc + (size_t)(b * D_ + d) * S_;
    const float* cp = dcum + (size_t)(b * D_ + d) * S_;
    const float* xp = x + (size_t)b * S_ * D_ + d;
    const float* bp = Bm + (size_t)b * S_ * N_ + n;
    const int t0 = ch * CHUNK_;

    float run = 0.f;
    if (PHASE_C)
        run = carry[(size_t)((b * D_ + d) * N_ + n) * NCHUNK_ + ch];
    float sum = 0.f;

    #pragma unroll 4
    for (int tt = 0; tt < CHUNK_; ++tt) {
        const int t = t0 + tt;
        float dsc = dp[t];
        float dcu = cp[t];
        float xv  = xp[(size_t)t * D_];
        float bm  = bp[(size_t)t * N_];

        float abar = expf(dsc * A);                 // A_bar
        float Bx   = bm * rA * (abar - 1.0f) * xv;  // B_bar * x
        float bxl  = logf(fabsf(Bx));
        float cum  = A * dcu;                       // cumsum of A_bar_pre
        float cl   = fmaxf(cum, bxl - 70.0f);       // LOG_CLAMP
        float mag  = expf(bxl - cl);
        float ai   = (Bx > 0.f) ? mag : ((Bx < 0.f) ? -mag : 0.f);

        if (PHASE_C) {
            run += ai;
            float h  = run * expf(cl);
            float yv = h * Cm[(size_t)(b * S_ + t) * N_ + n];
            // reduce over n within each 16-lane group
            yv += __shfl_xor(yv, 1, 16);
            yv += __shfl_xor(yv, 2, 16);
            yv += __shfl_xor(yv, 4, 16);
            yv += __shfl_xor(yv, 8, 16);
            if (n == 0) y[(size_t)(b * S_ + t) * D_ + d] = yv;
        } else {
            sum += ai;
        }
    }
    if (!PHASE_C)
        chunkSum[(size_t)((b * D_ + d) * N_ + n) * NCHUNK_ + ch] = sum;
}

// ---------------------------------------------------------------------------
// K3b: exclusive scan of chunk totals per channel (B*D*N = 8192 channels).
// ---------------------------------------------------------------------------
__global__ __launch_bounds__(256) void k3b_scan_chunks(
    const float* __restrict__ chunkSum, float* __restrict__ carry)
{
    const int idx = blockIdx.x * 256 + threadIdx.x;  // 0..8191
    const float* src = chunkSum + (size_t)idx * NCHUNK_;
    float* dst = carry + (size_t)idx * NCHUNK_;
    float run = 0.f;
    #pragma unroll
    for (int c = 0; c < NCHUNK_; ++c) {
        float v = src[c];
        dst[c] = run;
        run += v;
    }
}

// ---------------------------------------------------------------------------
extern "C" void kernel_launch(void* const* d_in, const int* in_sizes, int n_in,
                              void* d_out, int out_size, void* d_ws, size_t ws_size,
                              hipStream_t stream)
{
    const float* x    = (const float*)d_in[0];
    const float* Araw = (const float*)d_in[1];
    const float* P    = (const float*)d_in[2];
    const float* W_B  = (const float*)d_in[3];
    const float* b_B  = (const float*)d_in[4];
    const float* W_C  = (const float*)d_in[5];
    const float* b_C  = (const float*)d_in[6];
    const float* W_D  = (const float*)d_in[7];
    const float* b_D  = (const float*)d_in[8];
    float* y  = (float*)d_out;
    float* ws = (float*)d_ws;

    // workspace layout (floats) — total ~5.26M floats = ~21 MB
    float* xWD   = ws;                                   // B*S          = 16384
    float* Bm    = xWD  + B_ * S_;                       // B*S*N        = 262144
    float* Cm    = Bm   + B_ * S_ * N_;                  // B*S*N        = 262144
    float* disc  = Cm   + B_ * S_ * N_;                  // B*D*S        = 2097152
    float* dcum  = disc + B_ * D_ * S_;                  // B*D*S        = 2097152
    float* csum  = dcum + B_ * D_ * S_;                  // B*D*N*NCHUNK = 262144
    float* carry = csum + B_ * D_ * N_ * NCHUNK_;        // B*D*N*NCHUNK = 262144

    hipLaunchKernelGGL(k1_proj, dim3(B_ * S_ / 16), dim3(256), 0, stream,
                       x, W_B, b_B, W_C, b_C, W_D, b_D, xWD, Bm, Cm);
    hipLaunchKernelGGL(k2_scan_disc, dim3(B_ * D_), dim3(64), 0, stream,
                       xWD, P, disc, dcum);
    hipLaunchKernelGGL((k3_scan<0>), dim3(B_ * NCHUNK_ * (D_ / 16)), dim3(256), 0, stream,
                       x, Araw, Bm, Cm, disc, dcum, csum, carry, y);
    hipLaunchKernelGGL(k3b_scan_chunks, dim3(B_ * D_ * N_ / 256), dim3(256), 0, stream,
                       csum, carry);
    hipLaunchKernelGGL((k3_scan<1>), dim3(B_ * NCHUNK_ * (D_ / 16)), dim3(256), 0, stream,
                       x, Araw, Bm, Cm, disc, dcum, csum, carry, y);
}

// Round 2
// 108.939 us; speedup vs baseline: 1.8400x; 1.8400x over previous
//
#include <hip/hip_runtime.h>
#include <math.h>

// Problem constants (from reference)
#define B_ 4
#define S_ 4096
#define D_ 128
#define N_ 16
#define CHUNK_ 64
#define NCHUNK_ (S_ / CHUNK_)   // 64
#define NCHAN_ (B_ * D_ * N_)   // 8192
#define KC_ 64                  // k2 chunk length
#define KNC_ (S_ / KC_)         // 64 chunks

#define E70F  2.5154386709191672e+30f   // exp(70)
#define EM70F 3.9754497359086468e-31f   // exp(-70)
#define CAPF  3.0e38f

__device__ __forceinline__ float fast_sp(float z) {
    // softplus = max(z,0) + log1p(exp(-|z|)), fast HW transcendentals
    return fmaxf(z, 0.0f) + __logf(1.0f + __expf(-fabsf(z)));
}

template<int CTRL>
__device__ __forceinline__ float dpp_radd(float v) {
    int o = __builtin_amdgcn_mov_dpp(__float_as_int(v), CTRL, 0xf, 0xf, true);
    return v + __int_as_float(o);
}

// ---------------------------------------------------------------------------
// K1: per-row projections. xWD[b,t] = x@W_D + b_D ; Bm = x@W_B + b_B ;
//     Cm = x@W_C + b_C.  One block = 16 rows, 256 threads (16 rows x 16 cols).
// ---------------------------------------------------------------------------
__global__ __launch_bounds__(256) void k1_proj(
    const float* __restrict__ x,
    const float* __restrict__ W_B, const float* __restrict__ b_B,
    const float* __restrict__ W_C, const float* __restrict__ b_C,
    const float* __restrict__ W_D, const float* __restrict__ b_D,
    float* __restrict__ xWD, float* __restrict__ Bm, float* __restrict__ Cm)
{
    __shared__ float xs[16][129];
    const int row0 = blockIdx.x * 16;
    const int tid = threadIdx.x;

    #pragma unroll
    for (int i = 0; i < 8; ++i) {
        int idx = i * 256 + tid;
        xs[idx >> 7][idx & 127] = x[row0 * D_ + idx];
    }
    __syncthreads();

    const int r = tid >> 4;
    const int n = tid & 15;
    float a = 0.f, c = 0.f;
    #pragma unroll 4
    for (int k = 0; k < D_; ++k) {
        float xv = xs[r][k];
        a = fmaf(xv, W_B[k * N_ + n], a);
        c = fmaf(xv, W_C[k * N_ + n], c);
    }
    Bm[(row0 + r) * N_ + n] = a + b_B[n];
    Cm[(row0 + r) * N_ + n] = c + b_C[n];

    if (tid < 16) {
        float dsum = 0.f;
        #pragma unroll 4
        for (int k = 0; k < D_; ++k) dsum = fmaf(xs[tid][k], W_D[k], dsum);
        xWD[row0 + tid] = dsum + b_D[0];
    }
}

// ---------------------------------------------------------------------------
// K2 (chunked recompute): disc[bd,t] = softplus(P[d]+xWD[b,t]);
// dcum = inclusive cumsum over t.  a: per-chunk sums; b: scan; c: replay.
// ---------------------------------------------------------------------------
__global__ __launch_bounds__(256) void k2a(
    const float* __restrict__ xWD, const float* __restrict__ P,
    float* __restrict__ S2)
{
    int g = blockIdx.x * 256 + threadIdx.x;      // 0..32767
    int ch = g & (KNC_ - 1);
    int bd = g >> 6;
    int b = bd >> 7;
    int d = bd & (D_ - 1);
    float Pd = P[d];
    const float* xw = xWD + b * S_ + ch * KC_;
    float s = 0.f;
    #pragma unroll 8
    for (int i = 0; i < KC_; ++i) s += fast_sp(Pd + xw[i]);
    S2[g] = s;
}

__global__ __launch_bounds__(256) void k2b(
    const float* __restrict__ S2, float* __restrict__ carry2)
{
    int bd = blockIdx.x * 256 + threadIdx.x;     // 0..511
    const float* s = S2 + bd * KNC_;
    float* c = carry2 + bd * KNC_;
    float run = 0.f;
    #pragma unroll
    for (int i = 0; i < KNC_; ++i) { c[i] = run; run += s[i]; }
}

__global__ __launch_bounds__(256) void k2c(
    const float* __restrict__ xWD, const float* __restrict__ P,
    const float* __restrict__ carry2,
    float* __restrict__ disc, float* __restrict__ dcum)
{
    int g = blockIdx.x * 256 + threadIdx.x;
    int ch = g & (KNC_ - 1);
    int bd = g >> 6;
    int b = bd >> 7;
    int d = bd & (D_ - 1);
    float Pd = P[d];
    const float* xw = xWD + b * S_ + ch * KC_;
    float* dp = disc + (size_t)bd * S_ + ch * KC_;
    float* cp = dcum + (size_t)bd * S_ + ch * KC_;
    float run = carry2[g];
    #pragma unroll 4
    for (int i = 0; i < KC_; ++i) {
        float s = fast_sp(Pd + xw[i]);
        run += s;
        dp[i] = s;
        cp[i] = run;
    }
}

// ---------------------------------------------------------------------------
// K3: chunked scan over AinvsB (log-free formulation).
//  mag = min(|Bx|*exp(-cum), e70) ; clamped iff |Bx|*exp(-cum) > e70
//  ecl = clamped ? |Bx|*e^-70 : exp(cum)
// ---------------------------------------------------------------------------
template <int PHASE_C>
__global__ __launch_bounds__(256) void k3_scan(
    const float* __restrict__ x, const float* __restrict__ Araw,
    const float* __restrict__ Bm, const float* __restrict__ Cm,
    const float* __restrict__ disc, const float* __restrict__ dcum,
    float* __restrict__ chunkSum, const float* __restrict__ carry,
    float* __restrict__ y)
{
    const int blk = blockIdx.x;
    const int dg = blk & 7;
    const int ch = (blk >> 3) & (NCHUNK_ - 1);
    const int b  = blk >> 9;
    const int tid = threadIdx.x;
    const int n = tid & 15;
    const int dl = tid >> 4;
    const int d = dg * 16 + dl;
    const int cid = (b * D_ + d) * N_ + n;

    const float A  = -fast_sp(Araw[d * N_ + n]);   // strictly negative
    const float rA = 1.0f / A;
    const float nA = -A;

    const int t0 = ch * CHUNK_;
    const float* dp = disc + (size_t)(b * D_ + d) * S_ + t0;
    const float* cp = dcum + (size_t)(b * D_ + d) * S_ + t0;
    const float* xp = x + ((size_t)b * S_ + t0) * D_ + d;
    const float* bp = Bm + ((size_t)b * S_ + t0) * N_ + n;
    const float* Cp = Cm + ((size_t)b * S_ + t0) * N_ + n;
    float* yp = y + ((size_t)b * S_ + t0) * D_ + d;

    float run = 0.f;
    if (PHASE_C) run = carry[(size_t)ch * NCHAN_ + cid];

    #pragma unroll 4
    for (int tt = 0; tt < CHUNK_; ++tt) {
        float dsc = dp[tt];
        float dcu = cp[tt];
        float xv  = xp[(size_t)tt * D_];
        float bm  = bp[(size_t)tt * N_];

        float ab  = __expf(dsc * A);                 // A_bar in (0,1]
        float Bx  = (bm * rA) * (ab - 1.0f) * xv;    // B_bar * x
        float aBx = fabsf(Bx);
        float eneg, ecum;
        if (PHASE_C) {
            ecum = __expf(dcu * A);                  // exp(cum) <= 1
            eneg = fminf(__builtin_amdgcn_rcpf(ecum), CAPF);
        } else {
            ecum = 0.f;
            eneg = fminf(__expf(dcu * nA), CAPF);
        }
        float m   = aBx * eneg;
        float mag = fminf(m, E70F);
        float ai  = copysignf(mag, Bx);              // Bx==0 -> mag==0 -> +-0

        run += ai;
        if (PHASE_C) {
            float ecl = (m > E70F) ? aBx * EM70F : ecum;
            float yv = run * ecl * Cp[(size_t)tt * N_];
            yv = dpp_radd<0x121>(yv);   // row_ror:1
            yv = dpp_radd<0x122>(yv);   // row_ror:2
            yv = dpp_radd<0x124>(yv);   // row_ror:4
            yv = dpp_radd<0x128>(yv);   // row_ror:8
            if (n == 0) yp[(size_t)tt * D_] = yv;
        }
    }
    if (!PHASE_C) chunkSum[(size_t)ch * NCHAN_ + cid] = run;
}

// ---------------------------------------------------------------------------
// K3b: exclusive scan of chunk totals per channel, [ch][cid] layout.
// ---------------------------------------------------------------------------
__global__ __launch_bounds__(256) void k3b_scan_chunks(
    const float* __restrict__ csum, float* __restrict__ carry)
{
    int cid = blockIdx.x * 256 + threadIdx.x;    // 0..8191
    float run = 0.f;
    #pragma unroll
    for (int c = 0; c < NCHUNK_; ++c) {
        carry[(size_t)c * NCHAN_ + cid] = run;
        run += csum[(size_t)c * NCHAN_ + cid];
    }
}

// ---------------------------------------------------------------------------
extern "C" void kernel_launch(void* const* d_in, const int* in_sizes, int n_in,
                              void* d_out, int out_size, void* d_ws, size_t ws_size,
                              hipStream_t stream)
{
    const float* x    = (const float*)d_in[0];
    const float* Araw = (const float*)d_in[1];
    const float* P    = (const float*)d_in[2];
    const float* W_B  = (const float*)d_in[3];
    const float* b_B  = (const float*)d_in[4];
    const float* W_C  = (const float*)d_in[5];
    const float* b_C  = (const float*)d_in[6];
    const float* W_D  = (const float*)d_in[7];
    const float* b_D  = (const float*)d_in[8];
    float* y  = (float*)d_out;
    float* ws = (float*)d_ws;

    // workspace layout (floats) ~ 23.4 MB
    float* xWD    = ws;                                    // 16384
    float* Bm     = xWD  + B_ * S_;                        // 262144
    float* Cm     = Bm   + B_ * S_ * N_;                   // 262144
    float* disc   = Cm   + B_ * S_ * N_;                   // 2097152
    float* dcum   = disc + (size_t)B_ * D_ * S_;           // 2097152
    float* S2     = dcum + (size_t)B_ * D_ * S_;           // 32768
    float* carry2 = S2   + B_ * D_ * KNC_;                 // 32768
    float* csum   = carry2 + B_ * D_ * KNC_;               // 524288
    float* carry  = csum + (size_t)NCHAN_ * NCHUNK_;       // 524288

    hipLaunchKernelGGL(k1_proj, dim3(B_ * S_ / 16), dim3(256), 0, stream,
                       x, W_B, b_B, W_C, b_C, W_D, b_D, xWD, Bm, Cm);
    hipLaunchKernelGGL(k2a, dim3(B_ * D_ * KNC_ / 256), dim3(256), 0, stream,
                       xWD, P, S2);
    hipLaunchKernelGGL(k2b, dim3(B_ * D_ / 256), dim3(256), 0, stream,
                       S2, carry2);
    hipLaunchKernelGGL(k2c, dim3(B_ * D_ * KNC_ / 256), dim3(256), 0, stream,
                       xWD, P, carry2, disc, dcum);
    hipLaunchKernelGGL((k3_scan<0>), dim3(B_ * NCHUNK_ * (D_ / 16)), dim3(256), 0, stream,
                       x, Araw, Bm, Cm, disc, dcum, csum, carry, y);
    hipLaunchKernelGGL(k3b_scan_chunks, dim3(NCHAN_ / 256), dim3(256), 0, stream,
                       csum, carry);
    hipLaunchKernelGGL((k3_scan<1>), dim3(B_ * NCHUNK_ * (D_ / 16)), dim3(256), 0, stream,
                       x, Araw, Bm, Cm, disc, dcum, csum, carry, y);
}

// Round 3
// 104.587 us; speedup vs baseline: 1.9165x; 1.0416x over previous
//
#include <hip/hip_runtime.h>
#include <math.h>

// Problem constants (from reference)
#define B_ 4
#define S_ 4096
#define D_ 128
#define N_ 16
#define CHUNK_ 64
#define NCHUNK_ (S_ / CHUNK_)   // 64
#define NCHAN_ (B_ * D_ * N_)   // 8192
#define KC_ 32                  // k2 chunk length
#define KNC_ (S_ / KC_)         // 128 chunks

#define E70F  2.5154386709191672e+30f   // exp(70)
#define EM70F 3.9754497359086468e-31f   // exp(-70)
#define CAPF  3.0e38f
#define LOG2E 1.4426950408889634f

__device__ __forceinline__ float fast_sp(float z) {
    // softplus = max(z,0) + log1p(exp(-|z|)), fast HW transcendentals
    return fmaxf(z, 0.0f) + __logf(1.0f + __expf(-fabsf(z)));
}

__device__ __forceinline__ float exp2_hw(float x) {
#if __has_builtin(__builtin_amdgcn_exp2f)
    return __builtin_amdgcn_exp2f(x);
#else
    return exp2f(x);
#endif
}

template<int CTRL>
__device__ __forceinline__ float dpp_radd(float v) {
    int o = __builtin_amdgcn_mov_dpp(__float_as_int(v), CTRL, 0xf, 0xf, true);
    return v + __int_as_float(o);
}

// ---------------------------------------------------------------------------
// K1: projections + layout transposes.
//   xWD[b,t] = x@W_D + b_D ; BmT[b,n,t] = (x@W_B + b_B)^T ; CmT likewise;
//   xT[b,d,t] = x^T.  One block = 16 rows (t), 256 threads.
// ---------------------------------------------------------------------------
__global__ __launch_bounds__(256) void k1_proj(
    const float* __restrict__ x,
    const float* __restrict__ W_B, const float* __restrict__ b_B,
    const float* __restrict__ W_C, const float* __restrict__ b_C,
    const float* __restrict__ W_D, const float* __restrict__ b_D,
    float* __restrict__ xWD, float* __restrict__ BmT, float* __restrict__ CmT,
    float* __restrict__ xT)
{
    __shared__ float xs[16][129];
    const int row0 = blockIdx.x * 16;
    const int b  = row0 >> 12;          // S_=4096 rows per batch
    const int t0 = row0 & (S_ - 1);
    const int tid = threadIdx.x;

    #pragma unroll
    for (int i = 0; i < 8; ++i) {
        int idx = i * 256 + tid;
        xs[idx >> 7][idx & 127] = x[(size_t)row0 * D_ + idx];
    }
    __syncthreads();

    const int r = tid >> 4;
    const int n = tid & 15;
    float a = 0.f, c = 0.f;
    #pragma unroll 4
    for (int k = 0; k < D_; ++k) {
        float xv = xs[r][k];
        a = fmaf(xv, W_B[k * N_ + n], a);
        c = fmaf(xv, W_C[k * N_ + n], c);
    }
    BmT[(size_t)(b * N_ + n) * S_ + t0 + r] = a + b_B[n];
    CmT[(size_t)(b * N_ + n) * S_ + t0 + r] = c + b_C[n];

    if (tid < 16) {
        float dsum = 0.f;
        #pragma unroll 4
        for (int k = 0; k < D_; ++k) dsum = fmaf(xs[tid][k], W_D[k], dsum);
        xWD[row0 + tid] = dsum + b_D[0];
    }

    // x transpose: xT[b,d,t]
    const int tl = tid & 15;
    const int dh = tid >> 4;
    #pragma unroll
    for (int i = 0; i < 8; ++i) {
        int d = i * 16 + dh;
        xT[(size_t)(b * D_ + d) * S_ + t0 + tl] = xs[tl][d];
    }
}

// ---------------------------------------------------------------------------
// K2a: per-(bd,chunk32) sums of softplus(P[d]+xWD[b,t])  -> S2[bd,128]
// ---------------------------------------------------------------------------
__global__ __launch_bounds__(256) void k2a(
    const float* __restrict__ xWD, const float* __restrict__ P,
    float* __restrict__ S2)
{
    int g = blockIdx.x * 256 + threadIdx.x;      // 0..65535
    int ch = g & (KNC_ - 1);
    int bd = g >> 7;
    int bq = bd >> 7;
    int d  = bd & (D_ - 1);
    float Pd = P[d];
    const float* xw = xWD + bq * S_ + ch * KC_;
    float s = 0.f;
    #pragma unroll
    for (int i = 0; i < KC_; ++i) s += fast_sp(Pd + xw[i]);
    S2[g] = s;
}

// ---------------------------------------------------------------------------
// K2b: exclusive wave-scan of the 128 chunk sums per bd -> dstart[bd,128]
// ---------------------------------------------------------------------------
__global__ __launch_bounds__(64) void k2b(
    const float* __restrict__ S2, float* __restrict__ dstart)
{
    const int bd = blockIdx.x;
    const int lane = threadIdx.x;
    float v0 = S2[bd * KNC_ + lane * 2];
    float v1 = S2[bd * KNC_ + lane * 2 + 1];
    float s  = v0 + v1;
    float sc = s;
    #pragma unroll
    for (int off = 1; off < 64; off <<= 1) {
        float o = __shfl_up(sc, off);
        if (lane >= off) sc += o;
    }
    float excl = sc - s;
    dstart[bd * KNC_ + lane * 2]     = excl;
    dstart[bd * KNC_ + lane * 2 + 1] = excl + v0;
}

// ---------------------------------------------------------------------------
// K2c: elementwise disc[bd,t] = softplus(P[d] + xWD[b,t])  (coalesced)
// ---------------------------------------------------------------------------
__global__ __launch_bounds__(256) void k2c(
    const float* __restrict__ xWD, const float* __restrict__ P,
    float* __restrict__ disc)
{
    int e = blockIdx.x * 256 + threadIdx.x;      // 0..2M-1
    int t  = e & (S_ - 1);
    int bd = e >> 12;
    int bq = bd >> 7;
    int d  = bd & (D_ - 1);
    disc[e] = fast_sp(P[d] + xWD[bq * S_ + t]);
}

// ---------------------------------------------------------------------------
// K3: chunked scan over AinvsB, log2-domain, all streams channel-major.
//   cum2 tracked in-register (log2 units); eneg = min(exp2(-cum2),CAP);
//   mag = min(|Bx|*eneg, e70); ecl = clamped ? |Bx|e^-70 : rcp(eneg).
// ---------------------------------------------------------------------------
template <int PHASE_C>
__global__ __launch_bounds__(256) void k3_scan(
    const float* __restrict__ xT, const float* __restrict__ Araw,
    const float* __restrict__ BmT, const float* __restrict__ CmT,
    const float* __restrict__ disc, const float* __restrict__ dstart,
    float* __restrict__ chunkSum, const float* __restrict__ carry,
    float* __restrict__ y)
{
    const int blk = blockIdx.x;
    const int dg = blk & 7;                 // 8 d-groups
    const int ch = (blk >> 3) & (NCHUNK_ - 1);
    const int b  = blk >> 9;
    const int tid = threadIdx.x;
    const int n  = tid & 15;
    const int dl = tid >> 4;
    const int d  = dg * 16 + dl;
    const int bd = b * D_ + d;
    const int cid = bd * N_ + n;

    const float A  = -fast_sp(Araw[d * N_ + n]);   // strictly negative
    const float rA = 1.0f / A;
    const float A2 = A * LOG2E;                    // negative

    const int t0 = ch * CHUNK_;
    const float* dp = disc + (size_t)bd * S_ + t0;
    const float* xp = xT   + (size_t)bd * S_ + t0;
    const float* bp = BmT  + (size_t)(b * N_ + n) * S_ + t0;
    const float* Cp = CmT  + (size_t)(b * N_ + n) * S_ + t0;
    float* yp = y + ((size_t)b * S_ + t0) * D_ + d;

    // chunk-start cumulative (exclusive), in log2 units
    float cum2 = A2 * dstart[bd * KNC_ + ch * (CHUNK_ / KC_)];
    float run = 0.f;
    if (PHASE_C) run = carry[(size_t)ch * NCHAN_ + cid];

    for (int t4 = 0; t4 < CHUNK_ / 4; ++t4) {
        float dva[4], xva[4], bva[4], Cva[4];
        *(float4*)dva = ((const float4*)dp)[t4];
        *(float4*)xva = ((const float4*)xp)[t4];
        *(float4*)bva = ((const float4*)bp)[t4];
        if (PHASE_C) *(float4*)Cva = ((const float4*)Cp)[t4];

        #pragma unroll
        for (int j = 0; j < 4; ++j) {
            float t1 = dva[j] * A2;
            cum2 += t1;
            float ab  = exp2_hw(t1);                    // A_bar in (0,1]
            float Bx  = (bva[j] * rA) * (ab - 1.0f) * xva[j];
            float aBx = fabsf(Bx);
            float en  = fminf(exp2_hw(-cum2), CAPF);    // exp(-cum), capped
            float m   = aBx * en;
            run += copysignf(fminf(m, E70F), Bx);
            if (PHASE_C) {
                float ecl = (m > E70F) ? aBx * EM70F
                                       : __builtin_amdgcn_rcpf(en);
                float yv = run * ecl * Cva[j];
                yv = dpp_radd<0x121>(yv);   // row_ror:1
                yv = dpp_radd<0x122>(yv);   // row_ror:2
                yv = dpp_radd<0x124>(yv);   // row_ror:4
                yv = dpp_radd<0x128>(yv);   // row_ror:8
                if (n == 0) yp[(size_t)(t4 * 4 + j) * D_] = yv;
            }
        }
    }
    if (!PHASE_C) chunkSum[(size_t)ch * NCHAN_ + cid] = run;
}

// ---------------------------------------------------------------------------
// K3b: exclusive scan of chunk totals per channel, [ch][cid] layout.
// ---------------------------------------------------------------------------
__global__ __launch_bounds__(256) void k3b_scan_chunks(
    const float* __restrict__ csum, float* __restrict__ carry)
{
    int cid = blockIdx.x * 256 + threadIdx.x;    // 0..8191
    float run = 0.f;
    #pragma unroll
    for (int c = 0; c < NCHUNK_; ++c) {
        carry[(size_t)c * NCHAN_ + cid] = run;
        run += csum[(size_t)c * NCHAN_ + cid];
    }
}

// ---------------------------------------------------------------------------
extern "C" void kernel_launch(void* const* d_in, const int* in_sizes, int n_in,
                              void* d_out, int out_size, void* d_ws, size_t ws_size,
                              hipStream_t stream)
{
    const float* x    = (const float*)d_in[0];
    const float* Araw = (const float*)d_in[1];
    const float* P    = (const float*)d_in[2];
    const float* W_B  = (const float*)d_in[3];
    const float* b_B  = (const float*)d_in[4];
    const float* W_C  = (const float*)d_in[5];
    const float* b_C  = (const float*)d_in[6];
    const float* W_D  = (const float*)d_in[7];
    const float* b_D  = (const float*)d_in[8];
    float* y  = (float*)d_out;
    float* ws = (float*)d_ws;

    // workspace layout (floats) ~ 21.8 MB
    float* xWD    = ws;                                    // 16384
    float* BmT    = xWD  + B_ * S_;                        // 262144
    float* CmT    = BmT  + B_ * S_ * N_;                   // 262144
    float* xT     = CmT  + B_ * S_ * N_;                   // 2097152
    float* disc   = xT   + (size_t)B_ * D_ * S_;           // 2097152
    float* S2     = disc + (size_t)B_ * D_ * S_;           // 65536
    float* dstart = S2   + B_ * D_ * KNC_;                 // 65536
    float* csum   = dstart + B_ * D_ * KNC_;               // 524288
    float* carry  = csum + (size_t)NCHAN_ * NCHUNK_;       // 524288

    hipLaunchKernelGGL(k1_proj, dim3(B_ * S_ / 16), dim3(256), 0, stream,
                       x, W_B, b_B, W_C, b_C, W_D, b_D, xWD, BmT, CmT, xT);
    hipLaunchKernelGGL(k2a, dim3(B_ * D_ * KNC_ / 256), dim3(256), 0, stream,
                       xWD, P, S2);
    hipLaunchKernelGGL(k2b, dim3(B_ * D_), dim3(64), 0, stream,
                       S2, dstart);
    hipLaunchKernelGGL(k2c, dim3((size_t)B_ * D_ * S_ / 256), dim3(256), 0, stream,
                       xWD, P, disc);
    hipLaunchKernelGGL((k3_scan<0>), dim3(B_ * NCHUNK_ * (D_ / 16)), dim3(256), 0, stream,
                       xT, Araw, BmT, CmT, disc, dstart, csum, carry, y);
    hipLaunchKernelGGL(k3b_scan_chunks, dim3(NCHAN_ / 256), dim3(256), 0, stream,
                       csum, carry);
    hipLaunchKernelGGL((k3_scan<1>), dim3(B_ * NCHUNK_ * (D_ / 16)), dim3(256), 0, stream,
                       xT, Araw, BmT, CmT, disc, dstart, csum, carry, y);
}